// Round 7
// baseline (170.249 us; speedup 1.0000x reference)
//
#include <hip/hip_runtime.h>

#define NN 50000
#define NE 800000
#define GEMM_BLOCKS 782      // ceil(50000/64) rows of 64
#define SCAN_BLOCKS 49       // ceil(50000/1024)
#define NB 64                // counting-sort chunks
#define CHUNK ((NE + NB - 1) / NB)   // 12500 edges per block
#define HWORDS 12500         // packed u16-pair words per half-range (25000 nodes)

typedef unsigned short ushort_t;
typedef __attribute__((ext_vector_type(8))) short short8;       // 8 bf16 MFMA frag
typedef __attribute__((ext_vector_type(8))) unsigned short u16x8;
typedef __attribute__((ext_vector_type(4))) float f32x4;

__device__ __forceinline__ ushort_t f2bf(float f) {
    unsigned u = __float_as_uint(f);
    unsigned r = (u + 0x7fffu + ((u >> 16) & 1u)) >> 16;   // RNE
    return (ushort_t)r;
}
__device__ __forceinline__ float bf_lo(unsigned u) { return __uint_as_float(u << 16); }
__device__ __forceinline__ float bf_hi(unsigned u) { return __uint_as_float(u & 0xffff0000u); }
__device__ __forceinline__ float lrelu(float v) { return (v > 0.f) ? v : 0.2f * v; }
// LDS XOR swizzle for 256B-stride rows (kills ds_read_b128 bank conflicts)
__device__ __forceinline__ int swz(int b) { return b ^ (((b >> 8) & 7) << 4); }

// ---- K0: prep — Wt bf16 transpose [128][128] + folded logit vectors wa/ba ----
__global__ __launch_bounds__(256) void prep(
    const float* __restrict__ W, const float* __restrict__ bl,
    const float* __restrict__ alpha,
    ushort_t* __restrict__ Wt, float2* __restrict__ wa, float2* __restrict__ ba)
{
    int b = blockIdx.x;
    if (b < 64) {
        int idx = b * 256 + threadIdx.x;       // 16384 = 128*128
        int k = idx >> 7, n = idx & 127;
        Wt[n * 128 + k] = f2bf(W[k * 128 + n]);
    } else {
        int t = threadIdx.x;
        if (t < 128) {
            float s0 = 0.f, s1 = 0.f;
            for (int n = 0; n < 64; ++n) {
                s0 += W[t * 128 + n] * alpha[n];
                s1 += W[t * 128 + 64 + n] * alpha[64 + n];
            }
            wa[t] = make_float2(s0, s1);       // logit_h = nodes · wa[:,h] + ba[h]
        } else if (t == 128) {
            float s0 = 0.f, s1 = 0.f;
            for (int n = 0; n < 64; ++n) {
                s0 += bl[n] * alpha[n];
                s1 += bl[64 + n] * alpha[64 + n];
            }
            *ba = make_float2(s0, s1);
        }
    }
}

// ---- K1: MFMA GEMM (Xb = bf16(nodes@W + b)) + exact-fp32 a01 during staging --
__global__ __launch_bounds__(256) void gemm_x(
    const float* __restrict__ A, const ushort_t* __restrict__ Wt_g,
    const float* __restrict__ bl, const float2* __restrict__ wa,
    const float2* __restrict__ ba,
    ushort_t* __restrict__ Xb, float2* __restrict__ a01)
{
    __shared__ char lds[49152];       // [0,16K): An 64x128 bf16 ; [16K,48K): Wt 128x128 bf16
    const int t = threadIdx.x;
    const int r0 = blockIdx.x * 64;
    const int seg = t & 15;
    float2 wv[8];
#pragma unroll
    for (int j = 0; j < 8; ++j) wv[j] = wa[seg * 8 + j];
    const float2 bav = *ba;

#pragma unroll
    for (int it = 0; it < 4; ++it) {
        int row = it * 16 + (t >> 4);
        int r = r0 + row;
        float4 v0 = make_float4(0.f, 0.f, 0.f, 0.f), v1 = v0;
        if (r < NN) {
            v0 = *(const float4*)(A + (size_t)r * 128 + seg * 8);
            v1 = *(const float4*)(A + (size_t)r * 128 + seg * 8 + 4);
        }
        u16x8 p;
        p[0] = f2bf(v0.x); p[1] = f2bf(v0.y); p[2] = f2bf(v0.z); p[3] = f2bf(v0.w);
        p[4] = f2bf(v1.x); p[5] = f2bf(v1.y); p[6] = f2bf(v1.z); p[7] = f2bf(v1.w);
        *(u16x8*)(lds + swz(row * 256 + seg * 16)) = p;
        float p0 = v0.x * wv[0].x + v0.y * wv[1].x + v0.z * wv[2].x + v0.w * wv[3].x
                 + v1.x * wv[4].x + v1.y * wv[5].x + v1.z * wv[6].x + v1.w * wv[7].x;
        float p1 = v0.x * wv[0].y + v0.y * wv[1].y + v0.z * wv[2].y + v0.w * wv[3].y
                 + v1.x * wv[4].y + v1.y * wv[5].y + v1.z * wv[6].y + v1.w * wv[7].y;
#pragma unroll
        for (int d = 1; d < 16; d <<= 1) {
            p0 += __shfl_xor(p0, d);
            p1 += __shfl_xor(p1, d);
        }
        if (seg == 0 && r < NN)
            a01[r] = make_float2(lrelu(p0 + bav.x), lrelu(p1 + bav.y));
    }
#pragma unroll
    for (int it = 0; it < 8; ++it) {
        int id = it * 256 + t;
        int n = id >> 4, sg = id & 15;
        u16x8 p = *(const u16x8*)(Wt_g + n * 128 + sg * 8);
        *(u16x8*)(lds + swz(16384 + n * 256 + sg * 16)) = p;
    }
    __syncthreads();

    const int w = t >> 6, l = t & 63;
    const int lrow = l & 15, lk = l >> 4;
    f32x4 acc[8] = {f32x4{0,0,0,0}, f32x4{0,0,0,0}, f32x4{0,0,0,0}, f32x4{0,0,0,0},
                    f32x4{0,0,0,0}, f32x4{0,0,0,0}, f32x4{0,0,0,0}, f32x4{0,0,0,0}};
#pragma unroll
    for (int kc = 0; kc < 4; ++kc) {
        short8 bfrag = *(short8*)(lds + swz((w * 16 + lrow) * 256 + kc * 64 + lk * 16));
#pragma unroll
        for (int ct = 0; ct < 8; ++ct) {
            short8 afrag = *(short8*)(lds + swz(16384 + (ct * 16 + lrow) * 256 + kc * 64 + lk * 16));
            acc[ct] = __builtin_amdgcn_mfma_f32_16x16x32_bf16(afrag, bfrag, acc[ct], 0, 0, 0);
        }
    }
    const int r = r0 + w * 16 + lrow;
    if (r < NN) {
#pragma unroll
        for (int ct = 0; ct < 8; ++ct) {
            int c0 = ct * 16 + lk * 4;
            float4 b4 = *(const float4*)(bl + c0);
            ushort4 st;
            st.x = f2bf(acc[ct][0] + b4.x);
            st.y = f2bf(acc[ct][1] + b4.y);
            st.z = f2bf(acc[ct][2] + b4.z);
            st.w = f2bf(acc[ct][3] + b4.w);
            *(ushort4*)(Xb + (size_t)r * 128 + c0) = st;
        }
    }
}

// ---- K2: per-chunk LDS histogram (packed u16 pairs), zero global atomics ----
__global__ __launch_bounds__(256) void hist_lds(const int* __restrict__ rcv,
                                                ushort_t* __restrict__ hist_g)
{
    __shared__ unsigned hw[HWORDS];            // 50 KB: half of the 50000 bins
    const int b = blockIdx.x, t = threadIdx.x;
    const int e0 = b * CHUNK, e1 = min(NE, e0 + CHUNK);
#pragma unroll 1
    for (int half = 0; half < 2; ++half) {
        const int w0 = half * HWORDS;
        for (int i = t; i < HWORDS; i += 256) hw[i] = 0;
        __syncthreads();
        for (int i = e0 + t; i < e1; i += 256) {
            int r = rcv[i];
            int wdx = (r >> 1) - w0;
            if ((unsigned)wdx < HWORDS)
                atomicAdd(&hw[wdx], (r & 1) ? 0x10000u : 1u);  // low<=12500, no carry
        }
        __syncthreads();
        unsigned* dst = (unsigned*)hist_g + b * 25000 + w0;
        for (int i = t; i < HWORDS; i += 256) dst[i] = hw[i];
        __syncthreads();
    }
}

// ---- K3: column scan over block-rows -> per-(block,node) u16 base + deg -----
__global__ __launch_bounds__(256) void colscan(const ushort_t* __restrict__ hist_g,
                                               ushort_t* __restrict__ base16,
                                               int* __restrict__ deg)
{
    int n = blockIdx.x * 256 + threadIdx.x;
    if (n >= NN) return;
    unsigned run = 0;                          // max in-degree ~40 << 65536
#pragma unroll 1
    for (int b = 0; b < NB; ++b) {
        unsigned v = hist_g[b * 50000 + n];
        base16[b * 50000 + n] = (ushort_t)run;
        run += v;
    }
    deg[n] = (int)run;
}

// ---- K4a/b/c: exclusive scan of deg -> off ----------------------------------
__global__ __launch_bounds__(1024) void scan_partial(
    const int* __restrict__ cnt, int* __restrict__ off, int* __restrict__ bsum)
{
    __shared__ int wsum[16];
    const int t = threadIdx.x, lane = t & 63, wid = t >> 6;
    const int i = blockIdx.x * 1024 + t;
    int v = (i < NN) ? cnt[i] : 0;
    int incl = v;
#pragma unroll
    for (int d = 1; d < 64; d <<= 1) {
        int u = __shfl_up(incl, d);
        if (lane >= d) incl += u;
    }
    if (lane == 63) wsum[wid] = incl;
    __syncthreads();
    if (t < 16) {
        int w = wsum[t], wi = w;
#pragma unroll
        for (int d = 1; d < 16; d <<= 1) {
            int u = __shfl_up(wi, d);
            if (t >= d) wi += u;
        }
        wsum[t] = wi - w;
    }
    __syncthreads();
    int ex = wsum[wid] + (incl - v);
    if (i < NN) off[i] = ex;
    if (t == 1023) bsum[blockIdx.x] = ex + v;
}

__global__ __launch_bounds__(64) void scan_mid(int* __restrict__ bsum, int* __restrict__ boff,
                                               int* __restrict__ off)
{
    const int t = threadIdx.x;
    int v = (t < SCAN_BLOCKS) ? bsum[t] : 0;
    int incl = v;
#pragma unroll
    for (int d = 1; d < 64; d <<= 1) {
        int u = __shfl_up(incl, d);
        if (t >= d) incl += u;
    }
    if (t < SCAN_BLOCKS) boff[t] = incl - v;
    if (t == 0) off[NN] = NE;
}

__global__ __launch_bounds__(1024) void scan_add(int* __restrict__ off,
                                                 const int* __restrict__ boff)
{
    const int i = blockIdx.x * 1024 + threadIdx.x;
    if (i < NN) off[i] += boff[blockIdx.x];
}

__global__ __launch_bounds__(1024) void scan_add_seed(int* __restrict__ off,
                                                      const int* __restrict__ boff,
                                                      int* __restrict__ cur)
{
    const int i = blockIdx.x * 1024 + threadIdx.x;
    if (i < NN) {
        int o = off[i] + boff[blockIdx.x];
        off[i] = o;
        cur[i] = o;
    }
}

// ---- K5: scatter via LDS ranking (zero global atomics) ----------------------
__global__ __launch_bounds__(256) void scatter_cs(const int* __restrict__ snd,
                                                  const int* __restrict__ rcv,
                                                  const ushort_t* __restrict__ base16,
                                                  const int* __restrict__ off,
                                                  int* __restrict__ srt)
{
    __shared__ unsigned cw[HWORDS];
    const int b = blockIdx.x, t = threadIdx.x;
    const int e0 = b * CHUNK, e1 = min(NE, e0 + CHUNK);
#pragma unroll 1
    for (int half = 0; half < 2; ++half) {
        const int w0 = half * HWORDS;
        for (int i = t; i < HWORDS; i += 256) cw[i] = 0;
        __syncthreads();
        for (int i = e0 + t; i < e1; i += 256) {
            int r = rcv[i];
            int wdx = (r >> 1) - w0;
            if ((unsigned)wdx < HWORDS) {
                unsigned old = atomicAdd(&cw[wdx], (r & 1) ? 0x10000u : 1u);
                unsigned rank = (r & 1) ? (old >> 16) : (old & 0xffffu);
                srt[off[r] + (unsigned)base16[b * 50000 + r] + rank] = snd[i];
            }
        }
        __syncthreads();
    }
}

// ---- fallback (small-ws) atomic kernels -------------------------------------
__global__ __launch_bounds__(256) void hist_at(const int* __restrict__ rcv,
                                               int* __restrict__ cnt)
{
    int i = blockIdx.x * 256 + threadIdx.x;
    for (; i < NE; i += 512 * 256) atomicAdd(&cnt[rcv[i]], 1);
}

__global__ __launch_bounds__(256) void scatter_at(const int* __restrict__ snd,
                                                  const int* __restrict__ rcv,
                                                  int* __restrict__ cur,
                                                  int* __restrict__ srt)
{
    int i = blockIdx.x * 256 + threadIdx.x;
    if (i >= NE) return;
    int p = atomicAdd(&cur[rcv[i]], 1);
    srt[p] = snd[i];
}

// ---- K6: per-node aggregation, 4 edges per wave-iteration -------------------
__global__ __launch_bounds__(256) void aggregate(
    const ushort_t* __restrict__ Xb, const float2* __restrict__ a01,
    const int* __restrict__ off, const int* __restrict__ srt,
    const float* __restrict__ bias, float* __restrict__ out)
{
    const int n = blockIdx.x * 4 + (threadIdx.x >> 6);
    const int lane = threadIdx.x & 63;
    const int sub = lane >> 4;
    const int l16 = lane & 15;
    const int head = l16 >> 2;
    const bool soft = (head < 2);
    const int beg = off[n];
    const int deg = off[n + 1] - beg;
    const int total = deg + 1;               // + self loop

    float acc0 = 0.f, acc1 = 0.f, acc2 = 0.f, acc3 = 0.f;
    float acc4 = 0.f, acc5 = 0.f, acc6 = 0.f, acc7 = 0.f;
    float D = 0.f;

    for (int base = 0; base < total; base += 64) {
        int idx = base + lane;
        int sj = (idx < deg) ? srt[beg + idx] : n;
        float2 w2 = a01[sj];
        int cnt4 = min(64, total - base);
        int iters = (cnt4 + 3) >> 2;
#pragma unroll 2
        for (int d = 0; d < iters; ++d) {
            int e = 4 * d + sub;
            bool act = (e < cnt4);
            int   s   = __shfl(sj, e);
            float a0v = __shfl(w2.x, e);
            float a1v = __shfl(w2.y, e);
            float av  = (head == 0) ? a0v : a1v;
            float w   = act ? (soft ? __expf(av) : 1.0f) : 0.0f;
            D += w;
            uint4 u = *(const uint4*)(Xb + (size_t)s * 128 + l16 * 8);
            acc0 = fmaf(w, bf_lo(u.x), acc0);
            acc1 = fmaf(w, bf_hi(u.x), acc1);
            acc2 = fmaf(w, bf_lo(u.y), acc2);
            acc3 = fmaf(w, bf_hi(u.y), acc3);
            acc4 = fmaf(w, bf_lo(u.z), acc4);
            acc5 = fmaf(w, bf_hi(u.z), acc5);
            acc6 = fmaf(w, bf_lo(u.w), acc6);
            acc7 = fmaf(w, bf_hi(u.w), acc7);
        }
    }

    acc0 += __shfl_xor(acc0, 16); acc0 += __shfl_xor(acc0, 32);
    acc1 += __shfl_xor(acc1, 16); acc1 += __shfl_xor(acc1, 32);
    acc2 += __shfl_xor(acc2, 16); acc2 += __shfl_xor(acc2, 32);
    acc3 += __shfl_xor(acc3, 16); acc3 += __shfl_xor(acc3, 32);
    acc4 += __shfl_xor(acc4, 16); acc4 += __shfl_xor(acc4, 32);
    acc5 += __shfl_xor(acc5, 16); acc5 += __shfl_xor(acc5, 32);
    acc6 += __shfl_xor(acc6, 16); acc6 += __shfl_xor(acc6, 32);
    acc7 += __shfl_xor(acc7, 16); acc7 += __shfl_xor(acc7, 32);
    D    += __shfl_xor(D, 16);    D    += __shfl_xor(D, 32);

    if (sub == 0) {
        float scale = soft ? (1.0f / D) : (1.0f / (float)total);
        float4 b0 = *(const float4*)(bias + l16 * 8);
        float4 b1 = *(const float4*)(bias + l16 * 8 + 4);
        float4 o0 = make_float4(acc0 * scale + b0.x, acc1 * scale + b0.y,
                                acc2 * scale + b0.z, acc3 * scale + b0.w);
        float4 o1 = make_float4(acc4 * scale + b1.x, acc5 * scale + b1.y,
                                acc6 * scale + b1.z, acc7 * scale + b1.w);
        *(float4*)(out + (size_t)n * 128 + l16 * 8)     = o0;
        *(float4*)(out + (size_t)n * 128 + l16 * 8 + 4) = o1;
    }
}

// ------------------------------------------------------------------------------
extern "C" void kernel_launch(void* const* d_in, const int* in_sizes, int n_in,
                              void* d_out, int out_size, void* d_ws, size_t ws_size,
                              hipStream_t stream)
{
    const float* nodes     = (const float*)d_in[0];
    const int*   senders   = (const int*)d_in[1];
    const int*   receivers = (const int*)d_in[2];
    const float* W         = (const float*)d_in[3];
    const float* b_lin     = (const float*)d_in[4];
    const float* alpha     = (const float*)d_in[5];
    const float* bias      = (const float*)d_in[6];
    float* out = (float*)d_out;

    char* ws = (char*)d_ws;
    ushort_t* Xb     = (ushort_t*)(ws);                // 12,800,000
    float2*   a01    = (float2*)  (ws + 12800000);     //    400,000
    int*      deg    = (int*)     (ws + 13200000);     //    200,000 (cnt in fallback)
    int*      off    = (int*)     (ws + 13400000);     //    200,064
    int*      bsum   = (int*)     (ws + 13600064);     //        256
    int*      boff   = (int*)     (ws + 13600320);     //        256
    ushort_t* Wt_g   = (ushort_t*)(ws + 13600576);     //     32,768
    float2*   wa     = (float2*)  (ws + 13633344);     //      1,024
    float2*   ba     = (float2*)  (ws + 13634368);     //         64 (pad)
    ushort_t* hist_g = (ushort_t*)(ws + 13634432);     //  6,400,000
    int*      srt    = (int*)     (ws + 13634432);     //  3,200,000 (overlays hist_g; disjoint lifetime)
    ushort_t* base16 = (ushort_t*)(ws + 20034432);     //  6,400,000  -> end 26,434,432

    prep  <<<65, 256, 0, stream>>>(W, b_lin, alpha, Wt_g, wa, ba);
    gemm_x<<<GEMM_BLOCKS, 256, 0, stream>>>(nodes, Wt_g, b_lin, wa, ba, Xb, a01);

    if (ws_size >= 26434432ull) {
        // atomic-free counting sort
        hist_lds<<<NB, 256, 0, stream>>>(receivers, hist_g);
        colscan <<<(NN + 255) / 256, 256, 0, stream>>>(hist_g, base16, deg);
        scan_partial<<<SCAN_BLOCKS, 1024, 0, stream>>>(deg, off, bsum);
        scan_mid    <<<1, 64, 0, stream>>>(bsum, boff, off);
        scan_add    <<<SCAN_BLOCKS, 1024, 0, stream>>>(off, boff);
        scatter_cs<<<NB, 256, 0, stream>>>(senders, receivers, base16, off, srt);
    } else {
        // fallback: global-atomic path (round-6 behavior)
        hipMemsetAsync(deg, 0, NN * sizeof(int), stream);
        hist_at<<<512, 256, 0, stream>>>(receivers, deg);
        scan_partial<<<SCAN_BLOCKS, 1024, 0, stream>>>(deg, off, bsum);
        scan_mid    <<<1, 64, 0, stream>>>(bsum, boff, off);
        scan_add_seed<<<SCAN_BLOCKS, 1024, 0, stream>>>(off, boff, deg);
        scatter_at<<<(NE + 255) / 256, 256, 0, stream>>>(senders, receivers, deg, srt);
    }
    aggregate<<<(NN + 3) / 4, 256, 0, stream>>>(Xb, a01, off, srt, bias, out);
}

// Round 8
// 100.689 us; speedup vs baseline: 1.6908x; 1.6908x over previous
//
#include <hip/hip_runtime.h>

#define NN 50000
#define NE 800000
#define SCAT_BLOCKS 512
#define GEMM_BLOCKS 782      // ceil(50000/64) rows of 64
#define PREP_BLOCKS (65 + 196)

typedef unsigned short ushort_t;
typedef __attribute__((ext_vector_type(8))) short short8;       // 8 bf16 MFMA frag
typedef __attribute__((ext_vector_type(8))) unsigned short u16x8;
typedef __attribute__((ext_vector_type(4))) float f32x4;

__device__ __forceinline__ ushort_t f2bf(float f) {
    unsigned u = __float_as_uint(f);
    unsigned r = (u + 0x7fffu + ((u >> 16) & 1u)) >> 16;   // RNE
    return (ushort_t)r;
}
__device__ __forceinline__ float bf_lo(unsigned u) { return __uint_as_float(u << 16); }
__device__ __forceinline__ float bf_hi(unsigned u) { return __uint_as_float(u & 0xffff0000u); }
__device__ __forceinline__ float lrelu(float v) { return (v > 0.f) ? v : 0.2f * v; }
// LDS XOR swizzle for 256B-stride rows (kills ds_read_b128 bank conflicts)
__device__ __forceinline__ int swz(int b) { return b ^ (((b >> 8) & 7) << 4); }

// ---- K0: prep — Wt bf16 transpose + folded logit vectors wa/ba + cur init ----
__global__ __launch_bounds__(256) void prep(
    const float* __restrict__ W, const float* __restrict__ bl,
    const float* __restrict__ alpha,
    ushort_t* __restrict__ Wt, float2* __restrict__ wa, float2* __restrict__ ba,
    int* __restrict__ cur)
{
    int b = blockIdx.x;
    if (b < 64) {
        int idx = b * 256 + threadIdx.x;       // 16384 = 128*128
        int k = idx >> 7, n = idx & 127;
        Wt[n * 128 + k] = f2bf(W[k * 128 + n]);
    } else if (b == 64) {
        int t = threadIdx.x;
        if (t < 128) {
            float s0 = 0.f, s1 = 0.f;
            for (int n = 0; n < 64; ++n) {
                s0 += W[t * 128 + n] * alpha[n];
                s1 += W[t * 128 + 64 + n] * alpha[64 + n];
            }
            wa[t] = make_float2(s0, s1);       // logit_h = nodes · wa[:,h] + ba[h]
        } else if (t == 128) {
            float s0 = 0.f, s1 = 0.f;
            for (int n = 0; n < 64; ++n) {
                s0 += bl[n] * alpha[n];
                s1 += bl[64 + n] * alpha[64 + n];
            }
            *ba = make_float2(s0, s1);
        }
    } else {
        int n = (b - 65) * 256 + threadIdx.x;
        if (n < NN) cur[n] = n << 6;           // slot cursor = segment base (64/node)
    }
}

// ---- K1: fused  [scatter blocks: single atomic pass into padded slots]
//               + [GEMM blocks: MFMA Xb = bf16(nodes@W+b), exact-fp32 a01] ----
__global__ __launch_bounds__(256) void fused(
    const float* __restrict__ A,      // nodes [NN][128] fp32
    const ushort_t* __restrict__ Wt_g,// bf16 W^T [128][128]
    const float* __restrict__ bl,     // [128]
    const float2* __restrict__ wa,    // [128]
    const float2* __restrict__ ba,    // [1]
    const int* __restrict__ snd,      // [NE]
    const int* __restrict__ rcv,      // [NE]
    ushort_t* __restrict__ Xb,        // bf16 [NN][128]
    float2* __restrict__ a01,         // [NN]
    int* __restrict__ cur,            // [NN] slot cursors (pre-seeded 64n)
    int* __restrict__ srt)            // [NN*64] padded adjacency
{
    const int bid = blockIdx.x;
    const int t = threadIdx.x;

    if (bid < SCAT_BLOCKS) {
        // ---- the one atomic pass: scatter senders into per-receiver slots ----
        for (int i = bid * 256 + t; i < NE; i += SCAT_BLOCKS * 256) {
            int r = rcv[i];
            int p = atomicAdd(&cur[r], 1);
            if (p - (r << 6) < 64) srt[p] = snd[i];   // overflow guard (never fires)
        }
        return;
    }

    // ---------------- MFMA GEMM: 64 node-rows x 128 channels ----------------
    __shared__ char lds[49152];       // [0,16K): An 64x128 bf16 ; [16K,48K): Wt 128x128
    const int r0 = (bid - SCAT_BLOCKS) * 64;
    const int seg = t & 15;
    float2 wv[8];
#pragma unroll
    for (int j = 0; j < 8; ++j) wv[j] = wa[seg * 8 + j];
    const float2 bav = *ba;

#pragma unroll
    for (int it = 0; it < 4; ++it) {
        int row = it * 16 + (t >> 4);
        int r = r0 + row;
        float4 v0 = make_float4(0.f, 0.f, 0.f, 0.f), v1 = v0;
        if (r < NN) {
            v0 = *(const float4*)(A + (size_t)r * 128 + seg * 8);
            v1 = *(const float4*)(A + (size_t)r * 128 + seg * 8 + 4);
        }
        u16x8 p;
        p[0] = f2bf(v0.x); p[1] = f2bf(v0.y); p[2] = f2bf(v0.z); p[3] = f2bf(v0.w);
        p[4] = f2bf(v1.x); p[5] = f2bf(v1.y); p[6] = f2bf(v1.z); p[7] = f2bf(v1.w);
        *(u16x8*)(lds + swz(row * 256 + seg * 16)) = p;
        float p0 = v0.x * wv[0].x + v0.y * wv[1].x + v0.z * wv[2].x + v0.w * wv[3].x
                 + v1.x * wv[4].x + v1.y * wv[5].x + v1.z * wv[6].x + v1.w * wv[7].x;
        float p1 = v0.x * wv[0].y + v0.y * wv[1].y + v0.z * wv[2].y + v0.w * wv[3].y
                 + v1.x * wv[4].y + v1.y * wv[5].y + v1.z * wv[6].y + v1.w * wv[7].y;
#pragma unroll
        for (int d = 1; d < 16; d <<= 1) {
            p0 += __shfl_xor(p0, d);
            p1 += __shfl_xor(p1, d);
        }
        if (seg == 0 && r < NN)
            a01[r] = make_float2(lrelu(p0 + bav.x), lrelu(p1 + bav.y));
    }
#pragma unroll
    for (int it = 0; it < 8; ++it) {
        int id = it * 256 + t;
        int n = id >> 4, sg = id & 15;
        u16x8 p = *(const u16x8*)(Wt_g + n * 128 + sg * 8);
        *(u16x8*)(lds + swz(16384 + n * 256 + sg * 16)) = p;
    }
    __syncthreads();

    const int w = t >> 6, l = t & 63;
    const int lrow = l & 15, lk = l >> 4;
    f32x4 acc[8] = {f32x4{0,0,0,0}, f32x4{0,0,0,0}, f32x4{0,0,0,0}, f32x4{0,0,0,0},
                    f32x4{0,0,0,0}, f32x4{0,0,0,0}, f32x4{0,0,0,0}, f32x4{0,0,0,0}};
#pragma unroll
    for (int kc = 0; kc < 4; ++kc) {
        short8 bfrag = *(short8*)(lds + swz((w * 16 + lrow) * 256 + kc * 64 + lk * 16));
#pragma unroll
        for (int ct = 0; ct < 8; ++ct) {
            short8 afrag = *(short8*)(lds + swz(16384 + (ct * 16 + lrow) * 256 + kc * 64 + lk * 16));
            acc[ct] = __builtin_amdgcn_mfma_f32_16x16x32_bf16(afrag, bfrag, acc[ct], 0, 0, 0);
        }
    }
    const int r = r0 + w * 16 + lrow;
    if (r < NN) {
#pragma unroll
        for (int ct = 0; ct < 8; ++ct) {
            int c0 = ct * 16 + lk * 4;
            float4 b4 = *(const float4*)(bl + c0);
            ushort4 st;
            st.x = f2bf(acc[ct][0] + b4.x);
            st.y = f2bf(acc[ct][1] + b4.y);
            st.z = f2bf(acc[ct][2] + b4.z);
            st.w = f2bf(acc[ct][3] + b4.w);
            *(ushort4*)(Xb + (size_t)r * 128 + c0) = st;
        }
    }
}

// ---- K2: per-node aggregation, 4 edges per wave-iteration -------------------
// beg = 64n (padded slots), deg = cur[n] - 64n. lane layout as before.
__global__ __launch_bounds__(256) void aggregate(
    const ushort_t* __restrict__ Xb, const float2* __restrict__ a01,
    const int* __restrict__ cur, const int* __restrict__ srt,
    const float* __restrict__ bias, float* __restrict__ out)
{
    const int n = blockIdx.x * 4 + (threadIdx.x >> 6);
    const int lane = threadIdx.x & 63;
    const int sub = lane >> 4;
    const int l16 = lane & 15;
    const int head = l16 >> 2;
    const bool soft = (head < 2);
    const int beg = n << 6;
    const int deg = min(cur[n] - beg, 64);
    const int total = deg + 1;               // + self loop

    float acc0 = 0.f, acc1 = 0.f, acc2 = 0.f, acc3 = 0.f;
    float acc4 = 0.f, acc5 = 0.f, acc6 = 0.f, acc7 = 0.f;
    float D = 0.f;

    {
        int idx = lane;
        int sj = (idx < deg) ? srt[beg + idx] : n;   // slot idx==deg -> self loop
        float2 w2 = a01[sj];
        int cnt4 = total;                             // total <= 65; one batch (lane covers 64, self folded at idx==deg<=64... deg<=64 -> idx deg<=63 when deg<64; deg==64 handled below)
        int iters = (cnt4 + 3) >> 2;
#pragma unroll 2
        for (int d = 0; d < iters; ++d) {
            int e = 4 * d + sub;
            bool act = (e < cnt4);
            int   s   = __shfl(sj, e & 63);
            float a0v = __shfl(w2.x, e & 63);
            float a1v = __shfl(w2.y, e & 63);
            // e == 64 (only when deg==64): self loop, broadcast not usable -> handled after
            if (e == 64) { s = n; float2 wn = a01[n]; a0v = wn.x; a1v = wn.y; }
            float av  = (head == 0) ? a0v : a1v;
            float w   = act ? (soft ? __expf(av) : 1.0f) : 0.0f;
            D += w;
            uint4 u = *(const uint4*)(Xb + (size_t)s * 128 + l16 * 8);
            acc0 = fmaf(w, bf_lo(u.x), acc0);
            acc1 = fmaf(w, bf_hi(u.x), acc1);
            acc2 = fmaf(w, bf_lo(u.y), acc2);
            acc3 = fmaf(w, bf_hi(u.y), acc3);
            acc4 = fmaf(w, bf_lo(u.z), acc4);
            acc5 = fmaf(w, bf_hi(u.z), acc5);
            acc6 = fmaf(w, bf_lo(u.w), acc6);
            acc7 = fmaf(w, bf_hi(u.w), acc7);
        }
    }

    acc0 += __shfl_xor(acc0, 16); acc0 += __shfl_xor(acc0, 32);
    acc1 += __shfl_xor(acc1, 16); acc1 += __shfl_xor(acc1, 32);
    acc2 += __shfl_xor(acc2, 16); acc2 += __shfl_xor(acc2, 32);
    acc3 += __shfl_xor(acc3, 16); acc3 += __shfl_xor(acc3, 32);
    acc4 += __shfl_xor(acc4, 16); acc4 += __shfl_xor(acc4, 32);
    acc5 += __shfl_xor(acc5, 16); acc5 += __shfl_xor(acc5, 32);
    acc6 += __shfl_xor(acc6, 16); acc6 += __shfl_xor(acc6, 32);
    acc7 += __shfl_xor(acc7, 16); acc7 += __shfl_xor(acc7, 32);
    D    += __shfl_xor(D, 16);    D    += __shfl_xor(D, 32);

    if (sub == 0) {
        float scale = soft ? (1.0f / D) : (1.0f / (float)total);
        float4 b0 = *(const float4*)(bias + l16 * 8);
        float4 b1 = *(const float4*)(bias + l16 * 8 + 4);
        float4 o0 = make_float4(acc0 * scale + b0.x, acc1 * scale + b0.y,
                                acc2 * scale + b0.z, acc3 * scale + b0.w);
        float4 o1 = make_float4(acc4 * scale + b1.x, acc5 * scale + b1.y,
                                acc6 * scale + b1.z, acc7 * scale + b1.w);
        *(float4*)(out + (size_t)n * 128 + l16 * 8)     = o0;
        *(float4*)(out + (size_t)n * 128 + l16 * 8 + 4) = o1;
    }
}

// ------------------------------------------------------------------------------
extern "C" void kernel_launch(void* const* d_in, const int* in_sizes, int n_in,
                              void* d_out, int out_size, void* d_ws, size_t ws_size,
                              hipStream_t stream)
{
    const float* nodes     = (const float*)d_in[0];
    const int*   senders   = (const int*)d_in[1];
    const int*   receivers = (const int*)d_in[2];
    const float* W         = (const float*)d_in[3];
    const float* b_lin     = (const float*)d_in[4];
    const float* alpha     = (const float*)d_in[5];
    const float* bias      = (const float*)d_in[6];
    float* out = (float*)d_out;

    char* ws = (char*)d_ws;
    ushort_t* Xb   = (ushort_t*)(ws);               // 12,800,000
    float2*   a01  = (float2*)  (ws + 12800000);    //    400,000
    int*      cur  = (int*)     (ws + 13200000);    //    200,000
    ushort_t* Wt_g = (ushort_t*)(ws + 13400000);    //     32,768
    float2*   wa   = (float2*)  (ws + 13432768);    //      1,024
    float2*   ba   = (float2*)  (ws + 13433792);    //         64
    int*      srt  = (int*)     (ws + 13433856);    // 12,800,000 (64 slots/node) -> 26,233,856

    prep <<<PREP_BLOCKS, 256, 0, stream>>>(W, b_lin, alpha, Wt_g, wa, ba, cur);
    fused<<<SCAT_BLOCKS + GEMM_BLOCKS, 256, 0, stream>>>(
        nodes, Wt_g, b_lin, wa, ba, senders, receivers, Xb, a01, cur, srt);
    aggregate<<<(NN + 3) / 4, 256, 0, stream>>>(Xb, a01, cur, srt, bias, out);
}

// Round 9
// 97.079 us; speedup vs baseline: 1.7537x; 1.0372x over previous
//
#include <hip/hip_runtime.h>

#define NN 50000
#define NE 800000
#define SCAT_BLOCKS 512
#define GEMM_BLOCKS 782      // ceil(50000/64) rows of 64
#define PREP_BLOCKS (65 + 196)
#define CURS 16              // cur stride: one counter per 64B line

typedef unsigned short ushort_t;
typedef __attribute__((ext_vector_type(8))) short short8;       // 8 bf16 MFMA frag
typedef __attribute__((ext_vector_type(8))) unsigned short u16x8;
typedef __attribute__((ext_vector_type(4))) float f32x4;

__device__ __forceinline__ ushort_t f2bf(float f) {
    unsigned u = __float_as_uint(f);
    unsigned r = (u + 0x7fffu + ((u >> 16) & 1u)) >> 16;   // RNE
    return (ushort_t)r;
}
__device__ __forceinline__ float bf_lo(unsigned u) { return __uint_as_float(u << 16); }
__device__ __forceinline__ float bf_hi(unsigned u) { return __uint_as_float(u & 0xffff0000u); }
__device__ __forceinline__ float lrelu(float v) { return (v > 0.f) ? v : 0.2f * v; }
// LDS XOR swizzle for 256B-stride rows (kills ds_read_b128 bank conflicts)
__device__ __forceinline__ int swz(int b) { return b ^ (((b >> 8) & 7) << 4); }

// ---- K0: prep — Wt bf16 transpose + folded logit vectors wa/ba + cur init ----
__global__ __launch_bounds__(256) void prep(
    const float* __restrict__ W, const float* __restrict__ bl,
    const float* __restrict__ alpha,
    ushort_t* __restrict__ Wt, float2* __restrict__ wa, float2* __restrict__ ba,
    int* __restrict__ cur)
{
    int b = blockIdx.x;
    if (b < 64) {
        int idx = b * 256 + threadIdx.x;       // 16384 = 128*128
        int k = idx >> 7, n = idx & 127;
        Wt[n * 128 + k] = f2bf(W[k * 128 + n]);
    } else if (b == 64) {
        int t = threadIdx.x;
        if (t < 128) {
            float s0 = 0.f, s1 = 0.f;
            for (int n = 0; n < 64; ++n) {
                s0 += W[t * 128 + n] * alpha[n];
                s1 += W[t * 128 + 64 + n] * alpha[64 + n];
            }
            wa[t] = make_float2(s0, s1);       // logit_h = nodes · wa[:,h] + ba[h]
        } else if (t == 128) {
            float s0 = 0.f, s1 = 0.f;
            for (int n = 0; n < 64; ++n) {
                s0 += bl[n] * alpha[n];
                s1 += bl[64 + n] * alpha[64 + n];
            }
            *ba = make_float2(s0, s1);
        }
    } else {
        int n = (b - 65) * 256 + threadIdx.x;
        if (n < NN) cur[n * CURS] = n << 6;    // slot cursor = segment base (64/node)
    }
}

// ---- K1: fused  [scatter blocks: single atomic pass, line-padded counters]
//               + [GEMM blocks: MFMA Xb = bf16(nodes@W+b), exact-fp32 a01] ----
__global__ __launch_bounds__(256) void fused(
    const float* __restrict__ A,      // nodes [NN][128] fp32
    const ushort_t* __restrict__ Wt_g,// bf16 W^T [128][128]
    const float* __restrict__ bl,     // [128]
    const float2* __restrict__ wa,    // [128]
    const float2* __restrict__ ba,    // [1]
    const int* __restrict__ snd,      // [NE]
    const int* __restrict__ rcv,      // [NE]
    ushort_t* __restrict__ Xb,        // bf16 [NN][128]
    float2* __restrict__ a01,         // [NN]
    int* __restrict__ cur,            // [NN*CURS] padded slot cursors
    ushort_t* __restrict__ srt)       // [NN*64] padded adjacency (u16 sender ids)
{
    const int bid = blockIdx.x;
    const int t = threadIdx.x;

    if (bid < SCAT_BLOCKS) {
        // ---- the one atomic pass: 4 independent edges in flight per thread ----
        const int S = SCAT_BLOCKS * 256;
        int i0 = bid * 256 + t;
#pragma unroll 1
        for (int base = 0; base < 2; ++base) {
            int i = i0 + base * 4 * S;
            int r[4], sd[4], p[4];
            bool ok[4];
#pragma unroll
            for (int j = 0; j < 4; ++j) {
                int e = i + j * S;
                ok[j] = (e < NE);
                r[j]  = ok[j] ? rcv[e] : 0;
                sd[j] = ok[j] ? snd[e] : 0;
            }
#pragma unroll
            for (int j = 0; j < 4; ++j)
                if (ok[j]) p[j] = atomicAdd(&cur[r[j] * CURS], 1);
#pragma unroll
            for (int j = 0; j < 4; ++j)
                if (ok[j] && (p[j] - (r[j] << 6) < 64)) srt[p[j]] = (ushort_t)sd[j];
        }
        return;
    }

    // ---------------- MFMA GEMM: 64 node-rows x 128 channels ----------------
    __shared__ char lds[49152];       // [0,16K): An 64x128 bf16 ; [16K,48K): Wt 128x128
    const int r0 = (bid - SCAT_BLOCKS) * 64;
    const int seg = t & 15;
    float2 wv[8];
#pragma unroll
    for (int j = 0; j < 8; ++j) wv[j] = wa[seg * 8 + j];
    const float2 bav = *ba;

#pragma unroll
    for (int it = 0; it < 4; ++it) {
        int row = it * 16 + (t >> 4);
        int r = r0 + row;
        float4 v0 = make_float4(0.f, 0.f, 0.f, 0.f), v1 = v0;
        if (r < NN) {
            v0 = *(const float4*)(A + (size_t)r * 128 + seg * 8);
            v1 = *(const float4*)(A + (size_t)r * 128 + seg * 8 + 4);
        }
        u16x8 p;
        p[0] = f2bf(v0.x); p[1] = f2bf(v0.y); p[2] = f2bf(v0.z); p[3] = f2bf(v0.w);
        p[4] = f2bf(v1.x); p[5] = f2bf(v1.y); p[6] = f2bf(v1.z); p[7] = f2bf(v1.w);
        *(u16x8*)(lds + swz(row * 256 + seg * 16)) = p;
        float p0 = v0.x * wv[0].x + v0.y * wv[1].x + v0.z * wv[2].x + v0.w * wv[3].x
                 + v1.x * wv[4].x + v1.y * wv[5].x + v1.z * wv[6].x + v1.w * wv[7].x;
        float p1 = v0.x * wv[0].y + v0.y * wv[1].y + v0.z * wv[2].y + v0.w * wv[3].y
                 + v1.x * wv[4].y + v1.y * wv[5].y + v1.z * wv[6].y + v1.w * wv[7].y;
#pragma unroll
        for (int d = 1; d < 16; d <<= 1) {
            p0 += __shfl_xor(p0, d);
            p1 += __shfl_xor(p1, d);
        }
        if (seg == 0 && r < NN)
            a01[r] = make_float2(lrelu(p0 + bav.x), lrelu(p1 + bav.y));
    }
#pragma unroll
    for (int it = 0; it < 8; ++it) {
        int id = it * 256 + t;
        int n = id >> 4, sg = id & 15;
        u16x8 p = *(const u16x8*)(Wt_g + n * 128 + sg * 8);
        *(u16x8*)(lds + swz(16384 + n * 256 + sg * 16)) = p;
    }
    __syncthreads();

    const int w = t >> 6, l = t & 63;
    const int lrow = l & 15, lk = l >> 4;
    f32x4 acc[8] = {f32x4{0,0,0,0}, f32x4{0,0,0,0}, f32x4{0,0,0,0}, f32x4{0,0,0,0},
                    f32x4{0,0,0,0}, f32x4{0,0,0,0}, f32x4{0,0,0,0}, f32x4{0,0,0,0}};
#pragma unroll
    for (int kc = 0; kc < 4; ++kc) {
        short8 bfrag = *(short8*)(lds + swz((w * 16 + lrow) * 256 + kc * 64 + lk * 16));
#pragma unroll
        for (int ct = 0; ct < 8; ++ct) {
            short8 afrag = *(short8*)(lds + swz(16384 + (ct * 16 + lrow) * 256 + kc * 64 + lk * 16));
            acc[ct] = __builtin_amdgcn_mfma_f32_16x16x32_bf16(afrag, bfrag, acc[ct], 0, 0, 0);
        }
    }
    const int r = r0 + w * 16 + lrow;
    if (r < NN) {
#pragma unroll
        for (int ct = 0; ct < 8; ++ct) {
            int c0 = ct * 16 + lk * 4;
            float4 b4 = *(const float4*)(bl + c0);
            ushort4 st;
            st.x = f2bf(acc[ct][0] + b4.x);
            st.y = f2bf(acc[ct][1] + b4.y);
            st.z = f2bf(acc[ct][2] + b4.z);
            st.w = f2bf(acc[ct][3] + b4.w);
            *(ushort4*)(Xb + (size_t)r * 128 + c0) = st;
        }
    }
}

// ---- K2: per-node aggregation, 4 edges per wave-iteration -------------------
// beg = 64n (padded slots), deg = cur[n*CURS] - 64n. lane layout as before.
__global__ __launch_bounds__(256) void aggregate(
    const ushort_t* __restrict__ Xb, const float2* __restrict__ a01,
    const int* __restrict__ cur, const ushort_t* __restrict__ srt,
    const float* __restrict__ bias, float* __restrict__ out)
{
    const int n = blockIdx.x * 4 + (threadIdx.x >> 6);
    const int lane = threadIdx.x & 63;
    const int sub = lane >> 4;
    const int l16 = lane & 15;
    const int head = l16 >> 2;
    const bool soft = (head < 2);
    const int beg = n << 6;
    const int deg = min(cur[n * CURS] - beg, 64);
    const int total = deg + 1;               // + self loop

    float acc0 = 0.f, acc1 = 0.f, acc2 = 0.f, acc3 = 0.f;
    float acc4 = 0.f, acc5 = 0.f, acc6 = 0.f, acc7 = 0.f;
    float D = 0.f;

    {
        int idx = lane;
        int sj = (idx < deg) ? (int)srt[beg + idx] : n;   // slot idx==deg -> self
        float2 w2 = a01[sj];
        int cnt4 = total;                                  // <= 65
        int iters = (cnt4 + 3) >> 2;
#pragma unroll 2
        for (int d = 0; d < iters; ++d) {
            int e = 4 * d + sub;
            bool act = (e < cnt4);
            int   s   = __shfl(sj, e & 63);
            float a0v = __shfl(w2.x, e & 63);
            float a1v = __shfl(w2.y, e & 63);
            // e == 64 (only when deg==64): self loop slot beyond lane range
            if (e == 64) { s = n; float2 wn = a01[n]; a0v = wn.x; a1v = wn.y; }
            float av  = (head == 0) ? a0v : a1v;
            float w   = act ? (soft ? __expf(av) : 1.0f) : 0.0f;
            D += w;
            uint4 u = *(const uint4*)(Xb + (size_t)s * 128 + l16 * 8);
            acc0 = fmaf(w, bf_lo(u.x), acc0);
            acc1 = fmaf(w, bf_hi(u.x), acc1);
            acc2 = fmaf(w, bf_lo(u.y), acc2);
            acc3 = fmaf(w, bf_hi(u.y), acc3);
            acc4 = fmaf(w, bf_lo(u.z), acc4);
            acc5 = fmaf(w, bf_hi(u.z), acc5);
            acc6 = fmaf(w, bf_lo(u.w), acc6);
            acc7 = fmaf(w, bf_hi(u.w), acc7);
        }
    }

    acc0 += __shfl_xor(acc0, 16); acc0 += __shfl_xor(acc0, 32);
    acc1 += __shfl_xor(acc1, 16); acc1 += __shfl_xor(acc1, 32);
    acc2 += __shfl_xor(acc2, 16); acc2 += __shfl_xor(acc2, 32);
    acc3 += __shfl_xor(acc3, 16); acc3 += __shfl_xor(acc3, 32);
    acc4 += __shfl_xor(acc4, 16); acc4 += __shfl_xor(acc4, 32);
    acc5 += __shfl_xor(acc5, 16); acc5 += __shfl_xor(acc5, 32);
    acc6 += __shfl_xor(acc6, 16); acc6 += __shfl_xor(acc6, 32);
    acc7 += __shfl_xor(acc7, 16); acc7 += __shfl_xor(acc7, 32);
    D    += __shfl_xor(D, 16);    D    += __shfl_xor(D, 32);

    if (sub == 0) {
        float scale = soft ? (1.0f / D) : (1.0f / (float)total);
        float4 b0 = *(const float4*)(bias + l16 * 8);
        float4 b1 = *(const float4*)(bias + l16 * 8 + 4);
        float4 o0 = make_float4(acc0 * scale + b0.x, acc1 * scale + b0.y,
                                acc2 * scale + b0.z, acc3 * scale + b0.w);
        float4 o1 = make_float4(acc4 * scale + b1.x, acc5 * scale + b1.y,
                                acc6 * scale + b1.z, acc7 * scale + b1.w);
        *(float4*)(out + (size_t)n * 128 + l16 * 8)     = o0;
        *(float4*)(out + (size_t)n * 128 + l16 * 8 + 4) = o1;
    }
}

// ------------------------------------------------------------------------------
extern "C" void kernel_launch(void* const* d_in, const int* in_sizes, int n_in,
                              void* d_out, int out_size, void* d_ws, size_t ws_size,
                              hipStream_t stream)
{
    const float* nodes     = (const float*)d_in[0];
    const int*   senders   = (const int*)d_in[1];
    const int*   receivers = (const int*)d_in[2];
    const float* W         = (const float*)d_in[3];
    const float* b_lin     = (const float*)d_in[4];
    const float* alpha     = (const float*)d_in[5];
    const float* bias      = (const float*)d_in[6];
    float* out = (float*)d_out;

    char* ws = (char*)d_ws;
    ushort_t* Xb   = (ushort_t*)(ws);               // 12,800,000
    float2*   a01  = (float2*)  (ws + 12800000);    //    400,000
    int*      cur  = (int*)     (ws + 13200000);    //  3,200,000 (padded, 64B/counter)
    ushort_t* Wt_g = (ushort_t*)(ws + 16400000);    //     32,768
    float2*   wa   = (float2*)  (ws + 16432768);    //      1,024
    float2*   ba   = (float2*)  (ws + 16433792);    //         64
    ushort_t* srt  = (ushort_t*)(ws + 16433856);    //  6,400,000 (u16, 64 slots/node) -> 22,833,856

    prep <<<PREP_BLOCKS, 256, 0, stream>>>(W, b_lin, alpha, Wt_g, wa, ba, cur);
    fused<<<SCAT_BLOCKS + GEMM_BLOCKS, 256, 0, stream>>>(
        nodes, Wt_g, b_lin, wa, ba, senders, receivers, Xb, a01, cur, srt);
    aggregate<<<(NN + 3) / 4, 256, 0, stream>>>(Xb, a01, cur, srt, bias, out);
}

// Round 10
// 87.451 us; speedup vs baseline: 1.9468x; 1.1101x over previous
//
#include <hip/hip_runtime.h>

#define NN 50000
#define NE 800000
#define NSB 256                      // sort-prep blocks
#define CH (NE / NSB)                // 3125 edges per sort block
#define NBKT 1563                    // coarse buckets (32 receivers each)
#define N_SCAN (NBKT * NSB)          // 400128 hist entries
#define S1_BLOCKS ((N_SCAN + 1023) / 1024)   // 391
#define GEMM_BLOCKS 782              // ceil(50000/64)
#define PREP_BLOCKS 65

typedef unsigned short ushort_t;
typedef __attribute__((ext_vector_type(8))) short short8;       // 8 bf16 MFMA frag
typedef __attribute__((ext_vector_type(8))) unsigned short u16x8;
typedef __attribute__((ext_vector_type(4))) float f32x4;

__device__ __forceinline__ ushort_t f2bf(float f) {
    unsigned u = __float_as_uint(f);
    unsigned r = (u + 0x7fffu + ((u >> 16) & 1u)) >> 16;   // RNE
    return (ushort_t)r;
}
__device__ __forceinline__ float bf_lo(unsigned u) { return __uint_as_float(u << 16); }
__device__ __forceinline__ float bf_hi(unsigned u) { return __uint_as_float(u & 0xffff0000u); }
__device__ __forceinline__ float lrelu(float v) { return (v > 0.f) ? v : 0.2f * v; }
// LDS XOR swizzle for 256B-stride rows (kills ds_read_b128 bank conflicts)
__device__ __forceinline__ int swz(int b) { return b ^ (((b >> 8) & 7) << 4); }

// ---- K0: prep — Wt bf16 transpose + folded logit vectors wa/ba --------------
__global__ __launch_bounds__(256) void prep(
    const float* __restrict__ W, const float* __restrict__ bl,
    const float* __restrict__ alpha,
    ushort_t* __restrict__ Wt, float2* __restrict__ wa, float2* __restrict__ ba)
{
    int b = blockIdx.x;
    if (b < 64) {
        int idx = b * 256 + threadIdx.x;       // 16384 = 128*128
        int k = idx >> 7, n = idx & 127;
        Wt[n * 128 + k] = f2bf(W[k * 128 + n]);
    } else {
        int t = threadIdx.x;
        if (t < 128) {
            float s0 = 0.f, s1 = 0.f;
            for (int n = 0; n < 64; ++n) {
                s0 += W[t * 128 + n] * alpha[n];
                s1 += W[t * 128 + 64 + n] * alpha[64 + n];
            }
            wa[t] = make_float2(s0, s1);       // logit_h = nodes · wa[:,h] + ba[h]
        } else if (t == 128) {
            float s0 = 0.f, s1 = 0.f;
            for (int n = 0; n < 64; ++n) {
                s0 += bl[n] * alpha[n];
                s1 += bl[64 + n] * alpha[64 + n];
            }
            *ba = make_float2(s0, s1);
        }
    }
}

// ---- K1: fused [sort-prep: pack pk + bucket hist] + [MFMA GEMM + a01] -------
__global__ __launch_bounds__(256) void fused(
    const float* __restrict__ A,      // nodes [NN][128] fp32
    const ushort_t* __restrict__ Wt_g,// bf16 W^T [128][128]
    const float* __restrict__ bl,     // [128]
    const float2* __restrict__ wa,    // [128]
    const float2* __restrict__ ba,    // [1]
    const int* __restrict__ snd,      // [NE]
    const int* __restrict__ rcv,      // [NE]
    ushort_t* __restrict__ Xb,        // bf16 [NN][128]
    float2* __restrict__ a01,         // [NN]
    unsigned* __restrict__ pkA,       // [NE] packed (rcv<<16)|snd
    int* __restrict__ hist_g)         // [NBKT][NSB]
{
    __shared__ char lds[49152];
    const int bid = blockIdx.x;
    const int t = threadIdx.x;

    if (bid < NSB) {
        // ---------------- sort prep: pack + per-block bucket histogram --------
        int* hist = (int*)lds;                 // NBKT ints (6252 B)
        for (int i = t; i < NBKT; i += 256) hist[i] = 0;
        __syncthreads();
        const int e0 = bid * CH, e1 = e0 + CH;
        for (int i = e0 + t; i < e1; i += 256) {
            int r = rcv[i], s = snd[i];
            pkA[i] = ((unsigned)r << 16) | (unsigned)s;
            atomicAdd(&hist[r >> 5], 1);
        }
        __syncthreads();
        for (int bkt = t; bkt < NBKT; bkt += 256)
            hist_g[bkt * NSB + bid] = hist[bkt];
        return;
    }

    // ---------------- MFMA GEMM: 64 node-rows x 128 channels ----------------
    const int r0 = (bid - NSB) * 64;
    const int seg = t & 15;
    float2 wv[8];
#pragma unroll
    for (int j = 0; j < 8; ++j) wv[j] = wa[seg * 8 + j];
    const float2 bav = *ba;

#pragma unroll
    for (int it = 0; it < 4; ++it) {
        int row = it * 16 + (t >> 4);
        int r = r0 + row;
        float4 v0 = make_float4(0.f, 0.f, 0.f, 0.f), v1 = v0;
        if (r < NN) {
            v0 = *(const float4*)(A + (size_t)r * 128 + seg * 8);
            v1 = *(const float4*)(A + (size_t)r * 128 + seg * 8 + 4);
        }
        u16x8 p;
        p[0] = f2bf(v0.x); p[1] = f2bf(v0.y); p[2] = f2bf(v0.z); p[3] = f2bf(v0.w);
        p[4] = f2bf(v1.x); p[5] = f2bf(v1.y); p[6] = f2bf(v1.z); p[7] = f2bf(v1.w);
        *(u16x8*)(lds + swz(row * 256 + seg * 16)) = p;
        float p0 = v0.x * wv[0].x + v0.y * wv[1].x + v0.z * wv[2].x + v0.w * wv[3].x
                 + v1.x * wv[4].x + v1.y * wv[5].x + v1.z * wv[6].x + v1.w * wv[7].x;
        float p1 = v0.x * wv[0].y + v0.y * wv[1].y + v0.z * wv[2].y + v0.w * wv[3].y
                 + v1.x * wv[4].y + v1.y * wv[5].y + v1.z * wv[6].y + v1.w * wv[7].y;
#pragma unroll
        for (int d = 1; d < 16; d <<= 1) {
            p0 += __shfl_xor(p0, d);
            p1 += __shfl_xor(p1, d);
        }
        if (seg == 0 && r < NN)
            a01[r] = make_float2(lrelu(p0 + bav.x), lrelu(p1 + bav.y));
    }
#pragma unroll
    for (int it = 0; it < 8; ++it) {
        int id = it * 256 + t;
        int n = id >> 4, sg = id & 15;
        u16x8 p = *(const u16x8*)(Wt_g + n * 128 + sg * 8);
        *(u16x8*)(lds + swz(16384 + n * 256 + sg * 16)) = p;
    }
    __syncthreads();

    const int w = t >> 6, l = t & 63;
    const int lrow = l & 15, lk = l >> 4;
    f32x4 acc[8] = {f32x4{0,0,0,0}, f32x4{0,0,0,0}, f32x4{0,0,0,0}, f32x4{0,0,0,0},
                    f32x4{0,0,0,0}, f32x4{0,0,0,0}, f32x4{0,0,0,0}, f32x4{0,0,0,0}};
#pragma unroll
    for (int kc = 0; kc < 4; ++kc) {
        short8 bfrag = *(short8*)(lds + swz((w * 16 + lrow) * 256 + kc * 64 + lk * 16));
#pragma unroll
        for (int ct = 0; ct < 8; ++ct) {
            short8 afrag = *(short8*)(lds + swz(16384 + (ct * 16 + lrow) * 256 + kc * 64 + lk * 16));
            acc[ct] = __builtin_amdgcn_mfma_f32_16x16x32_bf16(afrag, bfrag, acc[ct], 0, 0, 0);
        }
    }
    const int r = r0 + w * 16 + lrow;
    if (r < NN) {
#pragma unroll
        for (int ct = 0; ct < 8; ++ct) {
            int c0 = ct * 16 + lk * 4;
            float4 b4 = *(const float4*)(bl + c0);
            ushort4 st;
            st.x = f2bf(acc[ct][0] + b4.x);
            st.y = f2bf(acc[ct][1] + b4.y);
            st.z = f2bf(acc[ct][2] + b4.z);
            st.w = f2bf(acc[ct][3] + b4.w);
            *(ushort4*)(Xb + (size_t)r * 128 + c0) = st;
        }
    }
}

// ---- S1: block-local exclusive scan of the 400128-entry hist matrix (in place)
__global__ __launch_bounds__(1024) void scan_p(int* __restrict__ data,
                                               int* __restrict__ bsum)
{
    __shared__ int wsum[16];
    const int t = threadIdx.x, lane = t & 63, wid = t >> 6;
    const int i = blockIdx.x * 1024 + t;
    int v = (i < N_SCAN) ? data[i] : 0;
    int incl = v;
#pragma unroll
    for (int d = 1; d < 64; d <<= 1) {
        int u = __shfl_up(incl, d);
        if (lane >= d) incl += u;
    }
    if (lane == 63) wsum[wid] = incl;
    __syncthreads();
    if (t < 16) {
        int w = wsum[t], wi = w;
#pragma unroll
        for (int d = 1; d < 16; d <<= 1) {
            int u = __shfl_up(wi, d);
            if (t >= d) wi += u;
        }
        wsum[t] = wi - w;
    }
    __syncthreads();
    int ex = wsum[wid] + (incl - v);
    if (i < N_SCAN) data[i] = ex;
    if (t == 1023) bsum[blockIdx.x] = ex + v;
}

// ---- S2: scan the 391 block totals (one block, 512 threads) -----------------
__global__ __launch_bounds__(512) void scan_m(const int* __restrict__ bsum,
                                              int* __restrict__ boff)
{
    __shared__ int wsum[8];
    const int t = threadIdx.x, lane = t & 63, wid = t >> 6;
    int v = (t < S1_BLOCKS) ? bsum[t] : 0;
    int incl = v;
#pragma unroll
    for (int d = 1; d < 64; d <<= 1) {
        int u = __shfl_up(incl, d);
        if (lane >= d) incl += u;
    }
    if (lane == 63) wsum[wid] = incl;
    __syncthreads();
    if (t < 8) {
        int w = wsum[t], wi = w;
#pragma unroll
        for (int d = 1; d < 8; d <<= 1) {
            int u = __shfl_up(wi, d);
            if (t >= d) wi += u;
        }
        wsum[t] = wi - w;
    }
    __syncthreads();
    if (t < S1_BLOCKS) boff[t] = wsum[wid] + (incl - v);
}

// ---- C: scatter pk into coarse buckets (LDS ranks, zero global atomics) -----
__global__ __launch_bounds__(256) void radix_scatter(
    const unsigned* __restrict__ pkA, const int* __restrict__ hist_g,
    const int* __restrict__ boff, unsigned* __restrict__ tmpB)
{
    __shared__ int rk[NBKT];
    const int blk = blockIdx.x, t = threadIdx.x;
    for (int i = t; i < NBKT; i += 256) rk[i] = 0;
    __syncthreads();
    const int e0 = blk * CH, e1 = e0 + CH;
    for (int i = e0 + t; i < e1; i += 256) {
        unsigned pk = pkA[i];
        int bkt = pk >> 21;
        int r = atomicAdd(&rk[bkt], 1);
        int idx = bkt * NSB + blk;
        int base = hist_g[idx] + boff[idx >> 10];
        tmpB[base + r] = pk;
    }
}

// ---- D: per-bucket finalize — exact off[] for 32 receivers + u16 srt --------
__global__ __launch_bounds__(256) void bucket_final(
    const unsigned* __restrict__ tmpB, const int* __restrict__ hist_g,
    const int* __restrict__ boff, int* __restrict__ off, ushort_t* __restrict__ srt)
{
    __shared__ int h32[32], pre[32], h32b[32];
    const int b = blockIdx.x, t = threadIdx.x;
    const int i0 = b * NSB;
    const int segbeg = hist_g[i0] + boff[i0 >> 10];
    const int segend = (b + 1 < NBKT) ? hist_g[(b + 1) * NSB] + boff[((b + 1) * NSB) >> 10]
                                      : NE;
    if (t < 32) { h32[t] = 0; h32b[t] = 0; }
    __syncthreads();
    for (int i = segbeg + t; i < segend; i += 256)
        atomicAdd(&h32[(tmpB[i] >> 16) & 31], 1);
    __syncthreads();
    if (t < 32) {
        int v = h32[t], incl = v;
#pragma unroll
        for (int d = 1; d < 32; d <<= 1) {
            int u = __shfl_up(incl, d);
            if (t >= d) incl += u;
        }
        pre[t] = incl - v;
        int node = b * 32 + t;
        if (node < NN) off[node] = segbeg + pre[t];
        if (b == NBKT - 1 && t == 0) off[NN] = NE;
    }
    __syncthreads();
    for (int i = segbeg + t; i < segend; i += 256) {
        unsigned pk = tmpB[i];
        int j = (pk >> 16) & 31;
        int rank = atomicAdd(&h32b[j], 1);
        srt[segbeg + pre[j] + rank] = (ushort_t)(pk & 0xffffu);
    }
}

// ---- K6: per-node aggregation (chunked, unbounded deg, u16 srt) -------------
__global__ __launch_bounds__(256) void aggregate(
    const ushort_t* __restrict__ Xb, const float2* __restrict__ a01,
    const int* __restrict__ off, const ushort_t* __restrict__ srt,
    const float* __restrict__ bias, float* __restrict__ out)
{
    const int n = blockIdx.x * 4 + (threadIdx.x >> 6);
    const int lane = threadIdx.x & 63;
    const int sub = lane >> 4;
    const int l16 = lane & 15;
    const int head = l16 >> 2;
    const bool soft = (head < 2);
    const int beg = off[n];
    const int deg = off[n + 1] - beg;
    const int total = deg + 1;               // + self loop

    float acc0 = 0.f, acc1 = 0.f, acc2 = 0.f, acc3 = 0.f;
    float acc4 = 0.f, acc5 = 0.f, acc6 = 0.f, acc7 = 0.f;
    float D = 0.f;

    for (int base = 0; base < total; base += 64) {
        int idx = base + lane;
        int sj = (idx < deg) ? (int)srt[beg + idx] : n;   // slot idx==deg -> self
        float2 w2 = a01[sj];
        int cnt4 = min(64, total - base);
        int iters = (cnt4 + 3) >> 2;
#pragma unroll 2
        for (int d = 0; d < iters; ++d) {
            int e = 4 * d + sub;
            bool act = (e < cnt4);
            int   s   = __shfl(sj, e);
            float a0v = __shfl(w2.x, e);
            float a1v = __shfl(w2.y, e);
            float av  = (head == 0) ? a0v : a1v;
            float w   = act ? (soft ? __expf(av) : 1.0f) : 0.0f;
            D += w;
            uint4 u = *(const uint4*)(Xb + (size_t)s * 128 + l16 * 8);
            acc0 = fmaf(w, bf_lo(u.x), acc0);
            acc1 = fmaf(w, bf_hi(u.x), acc1);
            acc2 = fmaf(w, bf_lo(u.y), acc2);
            acc3 = fmaf(w, bf_hi(u.y), acc3);
            acc4 = fmaf(w, bf_lo(u.z), acc4);
            acc5 = fmaf(w, bf_hi(u.z), acc5);
            acc6 = fmaf(w, bf_lo(u.w), acc6);
            acc7 = fmaf(w, bf_hi(u.w), acc7);
        }
    }

    acc0 += __shfl_xor(acc0, 16); acc0 += __shfl_xor(acc0, 32);
    acc1 += __shfl_xor(acc1, 16); acc1 += __shfl_xor(acc1, 32);
    acc2 += __shfl_xor(acc2, 16); acc2 += __shfl_xor(acc2, 32);
    acc3 += __shfl_xor(acc3, 16); acc3 += __shfl_xor(acc3, 32);
    acc4 += __shfl_xor(acc4, 16); acc4 += __shfl_xor(acc4, 32);
    acc5 += __shfl_xor(acc5, 16); acc5 += __shfl_xor(acc5, 32);
    acc6 += __shfl_xor(acc6, 16); acc6 += __shfl_xor(acc6, 32);
    acc7 += __shfl_xor(acc7, 16); acc7 += __shfl_xor(acc7, 32);
    D    += __shfl_xor(D, 16);    D    += __shfl_xor(D, 32);

    if (sub == 0) {
        float scale = soft ? (1.0f / D) : (1.0f / (float)total);
        float4 b0 = *(const float4*)(bias + l16 * 8);
        float4 b1 = *(const float4*)(bias + l16 * 8 + 4);
        float4 o0 = make_float4(acc0 * scale + b0.x, acc1 * scale + b0.y,
                                acc2 * scale + b0.z, acc3 * scale + b0.w);
        float4 o1 = make_float4(acc4 * scale + b1.x, acc5 * scale + b1.y,
                                acc6 * scale + b1.z, acc7 * scale + b1.w);
        *(float4*)(out + (size_t)n * 128 + l16 * 8)     = o0;
        *(float4*)(out + (size_t)n * 128 + l16 * 8 + 4) = o1;
    }
}

// ------------------------------------------------------------------------------
extern "C" void kernel_launch(void* const* d_in, const int* in_sizes, int n_in,
                              void* d_out, int out_size, void* d_ws, size_t ws_size,
                              hipStream_t stream)
{
    const float* nodes     = (const float*)d_in[0];
    const int*   senders   = (const int*)d_in[1];
    const int*   receivers = (const int*)d_in[2];
    const float* W         = (const float*)d_in[3];
    const float* b_lin     = (const float*)d_in[4];
    const float* alpha     = (const float*)d_in[5];
    const float* bias      = (const float*)d_in[6];
    float* out = (float*)d_out;

    char* ws = (char*)d_ws;
    ushort_t* Xb     = (ushort_t*)(ws);               // 12,800,000
    float2*   a01    = (float2*)  (ws + 12800000);    //    400,000
    int*      off    = (int*)     (ws + 13200000);    //    200,064
    ushort_t* Wt_g   = (ushort_t*)(ws + 13400064);    //     32,768
    float2*   wa     = (float2*)  (ws + 13432832);    //      1,024
    float2*   ba     = (float2*)  (ws + 13433856);    //         64
    int*      hist_g = (int*)     (ws + 13433920);    //  1,600,512
    int*      bsum   = (int*)     (ws + 15034432);    //      1,600
    int*      boff   = (int*)     (ws + 15036032);    //      1,600
    unsigned* pkA    = (unsigned*)(ws + 15037632);    //  3,200,000
    unsigned* tmpB   = (unsigned*)(ws + 18237632);    //  3,200,000
    ushort_t* srt    = (ushort_t*)(ws + 21437632);    //  1,600,000 -> 23,037,632

    prep <<<PREP_BLOCKS, 256, 0, stream>>>(W, b_lin, alpha, Wt_g, wa, ba);
    fused<<<NSB + GEMM_BLOCKS, 256, 0, stream>>>(
        nodes, Wt_g, b_lin, wa, ba, senders, receivers, Xb, a01, pkA, hist_g);
    scan_p<<<S1_BLOCKS, 1024, 0, stream>>>(hist_g, bsum);
    scan_m<<<1, 512, 0, stream>>>(bsum, boff);
    radix_scatter<<<NSB, 256, 0, stream>>>(pkA, hist_g, boff, tmpB);
    bucket_final <<<NBKT, 256, 0, stream>>>(tmpB, hist_g, boff, off, srt);
    aggregate<<<(NN + 3) / 4, 256, 0, stream>>>(Xb, a01, off, srt, bias, out);
}

// Round 11
// 80.391 us; speedup vs baseline: 2.1178x; 1.0878x over previous
//
#include <hip/hip_runtime.h>

#define NN 50000
#define NE 800000
#define NSB 256                      // sort-prep blocks
#define CH (NE / NSB)                // 3125 edges per sort block
#define NBKT 1563                    // coarse buckets (32 receivers each)
#define N_SCAN (NBKT * NSB)          // 400128 hist entries
#define S1_BLOCKS ((N_SCAN + 1023) / 1024)   // 391
#define GEMM_BLOCKS 782              // ceil(50000/64)
#define PREP_BLOCKS 65
#define CAP 768                      // bucket_agg LDS edge chunk

typedef unsigned short ushort_t;
typedef __attribute__((ext_vector_type(8))) short short8;       // 8 bf16 MFMA frag
typedef __attribute__((ext_vector_type(8))) unsigned short u16x8;
typedef __attribute__((ext_vector_type(4))) float f32x4;

__device__ __forceinline__ ushort_t f2bf(float f) {
    unsigned u = __float_as_uint(f);
    unsigned r = (u + 0x7fffu + ((u >> 16) & 1u)) >> 16;   // RNE
    return (ushort_t)r;
}
__device__ __forceinline__ float bf_lo(unsigned u) { return __uint_as_float(u << 16); }
__device__ __forceinline__ float bf_hi(unsigned u) { return __uint_as_float(u & 0xffff0000u); }
__device__ __forceinline__ float lrelu(float v) { return (v > 0.f) ? v : 0.2f * v; }
// LDS XOR swizzle for 256B-stride rows (kills ds_read_b128 bank conflicts)
__device__ __forceinline__ int swz(int b) { return b ^ (((b >> 8) & 7) << 4); }

// ---- K0: prep — Wt bf16 transpose + folded logit vectors wa/ba --------------
__global__ __launch_bounds__(256) void prep(
    const float* __restrict__ W, const float* __restrict__ bl,
    const float* __restrict__ alpha,
    ushort_t* __restrict__ Wt, float2* __restrict__ wa, float2* __restrict__ ba)
{
    int b = blockIdx.x;
    if (b < 64) {
        int idx = b * 256 + threadIdx.x;       // 16384 = 128*128
        int k = idx >> 7, n = idx & 127;
        Wt[n * 128 + k] = f2bf(W[k * 128 + n]);
    } else {
        int t = threadIdx.x;
        if (t < 128) {
            float s0 = 0.f, s1 = 0.f;
            for (int n = 0; n < 64; ++n) {
                s0 += W[t * 128 + n] * alpha[n];
                s1 += W[t * 128 + 64 + n] * alpha[64 + n];
            }
            wa[t] = make_float2(s0, s1);       // logit_h = nodes · wa[:,h] + ba[h]
        } else if (t == 128) {
            float s0 = 0.f, s1 = 0.f;
            for (int n = 0; n < 64; ++n) {
                s0 += bl[n] * alpha[n];
                s1 += bl[64 + n] * alpha[64 + n];
            }
            *ba = make_float2(s0, s1);
        }
    }
}

// ---- K1: fused [sort-prep: pack pk + bucket hist] + [MFMA GEMM + a01] -------
__global__ __launch_bounds__(256) void fused(
    const float* __restrict__ A,      // nodes [NN][128] fp32
    const ushort_t* __restrict__ Wt_g,// bf16 W^T [128][128]
    const float* __restrict__ bl,     // [128]
    const float2* __restrict__ wa,    // [128]
    const float2* __restrict__ ba,    // [1]
    const int* __restrict__ snd,      // [NE]
    const int* __restrict__ rcv,      // [NE]
    ushort_t* __restrict__ Xb,        // bf16 [NN][128]
    float2* __restrict__ a01,         // [NN]
    unsigned* __restrict__ pkA,       // [NE] packed (rcv<<16)|snd
    int* __restrict__ hist_g)         // [NBKT][NSB]
{
    __shared__ char lds[49152];
    const int bid = blockIdx.x;
    const int t = threadIdx.x;

    if (bid < NSB) {
        // ---------------- sort prep: pack + per-block bucket histogram --------
        int* hist = (int*)lds;                 // NBKT ints (6252 B)
        for (int i = t; i < NBKT; i += 256) hist[i] = 0;
        __syncthreads();
        const int e0 = bid * CH, e1 = e0 + CH;
        for (int i = e0 + t; i < e1; i += 256) {
            int r = rcv[i], s = snd[i];
            pkA[i] = ((unsigned)r << 16) | (unsigned)s;
            atomicAdd(&hist[r >> 5], 1);
        }
        __syncthreads();
        for (int bkt = t; bkt < NBKT; bkt += 256)
            hist_g[bkt * NSB + bid] = hist[bkt];
        return;
    }

    // ---------------- MFMA GEMM: 64 node-rows x 128 channels ----------------
    const int r0 = (bid - NSB) * 64;
    const int seg = t & 15;
    float2 wv[8];
#pragma unroll
    for (int j = 0; j < 8; ++j) wv[j] = wa[seg * 8 + j];
    const float2 bav = *ba;

#pragma unroll
    for (int it = 0; it < 4; ++it) {
        int row = it * 16 + (t >> 4);
        int r = r0 + row;
        float4 v0 = make_float4(0.f, 0.f, 0.f, 0.f), v1 = v0;
        if (r < NN) {
            v0 = *(const float4*)(A + (size_t)r * 128 + seg * 8);
            v1 = *(const float4*)(A + (size_t)r * 128 + seg * 8 + 4);
        }
        u16x8 p;
        p[0] = f2bf(v0.x); p[1] = f2bf(v0.y); p[2] = f2bf(v0.z); p[3] = f2bf(v0.w);
        p[4] = f2bf(v1.x); p[5] = f2bf(v1.y); p[6] = f2bf(v1.z); p[7] = f2bf(v1.w);
        *(u16x8*)(lds + swz(row * 256 + seg * 16)) = p;
        float p0 = v0.x * wv[0].x + v0.y * wv[1].x + v0.z * wv[2].x + v0.w * wv[3].x
                 + v1.x * wv[4].x + v1.y * wv[5].x + v1.z * wv[6].x + v1.w * wv[7].x;
        float p1 = v0.x * wv[0].y + v0.y * wv[1].y + v0.z * wv[2].y + v0.w * wv[3].y
                 + v1.x * wv[4].y + v1.y * wv[5].y + v1.z * wv[6].y + v1.w * wv[7].y;
#pragma unroll
        for (int d = 1; d < 16; d <<= 1) {
            p0 += __shfl_xor(p0, d);
            p1 += __shfl_xor(p1, d);
        }
        if (seg == 0 && r < NN)
            a01[r] = make_float2(lrelu(p0 + bav.x), lrelu(p1 + bav.y));
    }
#pragma unroll
    for (int it = 0; it < 8; ++it) {
        int id = it * 256 + t;
        int n = id >> 4, sg = id & 15;
        u16x8 p = *(const u16x8*)(Wt_g + n * 128 + sg * 8);
        *(u16x8*)(lds + swz(16384 + n * 256 + sg * 16)) = p;
    }
    __syncthreads();

    const int w = t >> 6, l = t & 63;
    const int lrow = l & 15, lk = l >> 4;
    f32x4 acc[8] = {f32x4{0,0,0,0}, f32x4{0,0,0,0}, f32x4{0,0,0,0}, f32x4{0,0,0,0},
                    f32x4{0,0,0,0}, f32x4{0,0,0,0}, f32x4{0,0,0,0}, f32x4{0,0,0,0}};
#pragma unroll
    for (int kc = 0; kc < 4; ++kc) {
        short8 bfrag = *(short8*)(lds + swz((w * 16 + lrow) * 256 + kc * 64 + lk * 16));
#pragma unroll
        for (int ct = 0; ct < 8; ++ct) {
            short8 afrag = *(short8*)(lds + swz(16384 + (ct * 16 + lrow) * 256 + kc * 64 + lk * 16));
            acc[ct] = __builtin_amdgcn_mfma_f32_16x16x32_bf16(afrag, bfrag, acc[ct], 0, 0, 0);
        }
    }
    const int r = r0 + w * 16 + lrow;
    if (r < NN) {
#pragma unroll
        for (int ct = 0; ct < 8; ++ct) {
            int c0 = ct * 16 + lk * 4;
            float4 b4 = *(const float4*)(bl + c0);
            ushort4 st;
            st.x = f2bf(acc[ct][0] + b4.x);
            st.y = f2bf(acc[ct][1] + b4.y);
            st.z = f2bf(acc[ct][2] + b4.z);
            st.w = f2bf(acc[ct][3] + b4.w);
            *(ushort4*)(Xb + (size_t)r * 128 + c0) = st;
        }
    }
}

// ---- S1: block-local exclusive scan of the 400128-entry hist matrix (in place)
__global__ __launch_bounds__(1024) void scan_p(int* __restrict__ data,
                                               int* __restrict__ bsum)
{
    __shared__ int wsum[16];
    const int t = threadIdx.x, lane = t & 63, wid = t >> 6;
    const int i = blockIdx.x * 1024 + t;
    int v = (i < N_SCAN) ? data[i] : 0;
    int incl = v;
#pragma unroll
    for (int d = 1; d < 64; d <<= 1) {
        int u = __shfl_up(incl, d);
        if (lane >= d) incl += u;
    }
    if (lane == 63) wsum[wid] = incl;
    __syncthreads();
    if (t < 16) {
        int w = wsum[t], wi = w;
#pragma unroll
        for (int d = 1; d < 16; d <<= 1) {
            int u = __shfl_up(wi, d);
            if (t >= d) wi += u;
        }
        wsum[t] = wi - w;
    }
    __syncthreads();
    int ex = wsum[wid] + (incl - v);
    if (i < N_SCAN) data[i] = ex;
    if (t == 1023) bsum[blockIdx.x] = ex + v;
}

// ---- S2: scan the 391 block totals (one block, 512 threads) -----------------
__global__ __launch_bounds__(512) void scan_m(const int* __restrict__ bsum,
                                              int* __restrict__ boff)
{
    __shared__ int wsum[8];
    const int t = threadIdx.x, lane = t & 63, wid = t >> 6;
    int v = (t < S1_BLOCKS) ? bsum[t] : 0;
    int incl = v;
#pragma unroll
    for (int d = 1; d < 64; d <<= 1) {
        int u = __shfl_up(incl, d);
        if (lane >= d) incl += u;
    }
    if (lane == 63) wsum[wid] = incl;
    __syncthreads();
    if (t < 8) {
        int w = wsum[t], wi = w;
#pragma unroll
        for (int d = 1; d < 8; d <<= 1) {
            int u = __shfl_up(wi, d);
            if (t >= d) wi += u;
        }
        wsum[t] = wi - w;
    }
    __syncthreads();
    if (t < S1_BLOCKS) boff[t] = wsum[wid] + (incl - v);
}

// ---- C: scatter pk into coarse buckets (LDS ranks, zero global atomics) -----
__global__ __launch_bounds__(1024) void radix_scatter(
    const unsigned* __restrict__ pkA, const int* __restrict__ hist_g,
    const int* __restrict__ boff, unsigned* __restrict__ tmpB)
{
    __shared__ int rk[NBKT];
    const int blk = blockIdx.x, t = threadIdx.x;
    for (int i = t; i < NBKT; i += 1024) rk[i] = 0;
    __syncthreads();
    const int e0 = blk * CH, e1 = e0 + CH;
    for (int i = e0 + t; i < e1; i += 1024) {
        unsigned pk = pkA[i];
        int bkt = pk >> 21;
        int r = atomicAdd(&rk[bkt], 1);
        int idx = bkt * NSB + blk;
        int base = hist_g[idx] + boff[idx >> 10];
        tmpB[base + r] = pk;
    }
}

// ---- K5: bucket_agg — per-bucket finalize + aggregation, fused --------------
// Block = one bucket (32 consecutive receivers). Stage edges into LDS grouped
// by local receiver (exp computed once per edge); 16-lane subgroup per node.
__global__ __launch_bounds__(256) void bucket_agg(
    const unsigned* __restrict__ tmpB, const int* __restrict__ hist_g,
    const int* __restrict__ boff,
    const ushort_t* __restrict__ Xb, const float2* __restrict__ a01,
    const float* __restrict__ bias, float* __restrict__ out)
{
    __shared__ int cnt32[32], pre32[32], rkpos[32];
    __shared__ ushort_t lsnd[CAP];
    __shared__ float2 lw[CAP];

    const int b = blockIdx.x, t = threadIdx.x;
    const int i0 = b * NSB;
    const int segbeg = hist_g[i0] + boff[i0 >> 10];
    const int nxt = (b + 1) * NSB;
    const int segend = (b < NBKT - 1) ? (hist_g[nxt] + boff[nxt >> 10]) : NE;

    const int sg = t >> 4;          // subgroup 0..15
    const int l16 = t & 15;         // channel group: ch l16*8 .. +7
    const int head = l16 >> 2;
    const bool soft = (head < 2);

    float accA[8] = {0,0,0,0,0,0,0,0};   // node sg
    float accB[8] = {0,0,0,0,0,0,0,0};   // node sg+16
    float DA = 0.f, DB = 0.f;

    for (int cbeg = segbeg; cbeg < segend; cbeg += CAP) {
        const int m = min(CAP, segend - cbeg);
        if (t < 32) cnt32[t] = 0;
        __syncthreads();
        unsigned pkr[3]; int nv = 0;
        for (int i = t; i < m; i += 256) {
            unsigned pk = tmpB[cbeg + i];
            pkr[nv++] = pk;
            atomicAdd(&cnt32[(pk >> 16) & 31], 1);
        }
        __syncthreads();
        if (t < 32) {
            int v = cnt32[t], incl = v;
#pragma unroll
            for (int d = 1; d < 32; d <<= 1) {
                int u = __shfl_up(incl, d);
                if (t >= d) incl += u;
            }
            pre32[t] = incl - v;
            rkpos[t] = incl - v;
        }
        __syncthreads();
        for (int j = 0; j < nv; ++j) {
            unsigned pk = pkr[j];
            int bkt = (pk >> 16) & 31;
            int sd = pk & 0xffff;
            int pos = atomicAdd(&rkpos[bkt], 1);
            float2 a = a01[sd];
            lsnd[pos] = (ushort_t)sd;
            lw[pos] = make_float2(__expf(a.x), __expf(a.y));
        }
        __syncthreads();

        // compute: subgroup sg handles local nodes sg (->accA) and sg+16 (->accB)
        auto body = [&](float (&acc)[8], float& D, int j) {
            const int s = pre32[j], cn = cnt32[j];
            for (int i = 0; i < cn; ++i) {
                float2 w2 = lw[s + i];
                int sd = lsnd[s + i];
                float w = soft ? ((head == 0) ? w2.x : w2.y) : 1.0f;
                D += w;
                uint4 u = *(const uint4*)(Xb + (size_t)sd * 128 + l16 * 8);
                acc[0] = fmaf(w, bf_lo(u.x), acc[0]);
                acc[1] = fmaf(w, bf_hi(u.x), acc[1]);
                acc[2] = fmaf(w, bf_lo(u.y), acc[2]);
                acc[3] = fmaf(w, bf_hi(u.y), acc[3]);
                acc[4] = fmaf(w, bf_lo(u.z), acc[4]);
                acc[5] = fmaf(w, bf_hi(u.z), acc[5]);
                acc[6] = fmaf(w, bf_lo(u.w), acc[6]);
                acc[7] = fmaf(w, bf_hi(u.w), acc[7]);
            }
        };
        body(accA, DA, sg);
        body(accB, DB, sg + 16);
        __syncthreads();     // protect LDS before next chunk
    }

    // finalize: self loop + scale + bias + store
    auto fin = [&](float (&acc)[8], float& D, int j) {
        const int n = b * 32 + j;
        if (n >= NN) return;
        float2 a = a01[n];
        float w = soft ? ((head == 0) ? __expf(a.x) : __expf(a.y)) : 1.0f;
        D += w;
        uint4 u = *(const uint4*)(Xb + (size_t)n * 128 + l16 * 8);
        acc[0] = fmaf(w, bf_lo(u.x), acc[0]);
        acc[1] = fmaf(w, bf_hi(u.x), acc[1]);
        acc[2] = fmaf(w, bf_lo(u.y), acc[2]);
        acc[3] = fmaf(w, bf_hi(u.y), acc[3]);
        acc[4] = fmaf(w, bf_lo(u.z), acc[4]);
        acc[5] = fmaf(w, bf_hi(u.z), acc[5]);
        acc[6] = fmaf(w, bf_lo(u.w), acc[6]);
        acc[7] = fmaf(w, bf_hi(u.w), acc[7]);
        float scale = 1.0f / D;     // soft lanes: softmax denom; mean lanes: deg+1
        float4 b0 = *(const float4*)(bias + l16 * 8);
        float4 b1 = *(const float4*)(bias + l16 * 8 + 4);
        float4 o0 = make_float4(acc[0] * scale + b0.x, acc[1] * scale + b0.y,
                                acc[2] * scale + b0.z, acc[3] * scale + b0.w);
        float4 o1 = make_float4(acc[4] * scale + b1.x, acc[5] * scale + b1.y,
                                acc[6] * scale + b1.z, acc[7] * scale + b1.w);
        *(float4*)(out + (size_t)n * 128 + l16 * 8)     = o0;
        *(float4*)(out + (size_t)n * 128 + l16 * 8 + 4) = o1;
    };
    fin(accA, DA, sg);
    fin(accB, DB, sg + 16);
}

// ------------------------------------------------------------------------------
extern "C" void kernel_launch(void* const* d_in, const int* in_sizes, int n_in,
                              void* d_out, int out_size, void* d_ws, size_t ws_size,
                              hipStream_t stream)
{
    const float* nodes     = (const float*)d_in[0];
    const int*   senders   = (const int*)d_in[1];
    const int*   receivers = (const int*)d_in[2];
    const float* W         = (const float*)d_in[3];
    const float* b_lin     = (const float*)d_in[4];
    const float* alpha     = (const float*)d_in[5];
    const float* bias      = (const float*)d_in[6];
    float* out = (float*)d_out;

    char* ws = (char*)d_ws;
    ushort_t* Xb     = (ushort_t*)(ws);               // 12,800,000
    float2*   a01    = (float2*)  (ws + 12800000);    //    400,000
    ushort_t* Wt_g   = (ushort_t*)(ws + 13200000);    //     32,768
    float2*   wa     = (float2*)  (ws + 13232768);    //      1,024
    float2*   ba     = (float2*)  (ws + 13233792);    //         64
    int*      hist_g = (int*)     (ws + 13233856);    //  1,600,512
    int*      bsum   = (int*)     (ws + 14834368);    //      1,600
    int*      boff   = (int*)     (ws + 14835968);    //      1,600
    unsigned* pkA    = (unsigned*)(ws + 14837568);    //  3,200,000
    unsigned* tmpB   = (unsigned*)(ws + 18037568);    //  3,200,000 -> 21,237,568

    prep <<<PREP_BLOCKS, 256, 0, stream>>>(W, b_lin, alpha, Wt_g, wa, ba);
    fused<<<NSB + GEMM_BLOCKS, 256, 0, stream>>>(
        nodes, Wt_g, b_lin, wa, ba, senders, receivers, Xb, a01, pkA, hist_g);
    scan_p<<<S1_BLOCKS, 1024, 0, stream>>>(hist_g, bsum);
    scan_m<<<1, 512, 0, stream>>>(bsum, boff);
    radix_scatter<<<NSB, 1024, 0, stream>>>(pkA, hist_g, boff, tmpB);
    bucket_agg<<<NBKT, 256, 0, stream>>>(tmpB, hist_g, boff, Xb, a01, bias, out);
}